// Round 7
// baseline (518.916 us; speedup 1.0000x reference)
//
#include <hip/hip_runtime.h>
#include <hip/hip_bf16.h>
#include <stdint.h>
#include <stddef.h>

// HoloLinear factored bf16 MFMA pipeline — MEASUREMENT ROUND:
// identical kernels to round 6, but gemm2_pipe is launched 3x (idempotent)
// to decompose total time:  g2 = (dur_new - 210)/2.
//
//   resonance[16384,256] = x_f32[16384,2048] @ basis_bf16[256,2048]^T
//   out[16384,8192]      = resonance_bf16 @ wreal_bf16[8192,256]^T

typedef __bf16 bf16x8 __attribute__((ext_vector_type(8)));
typedef float  f32x4  __attribute__((ext_vector_type(4)));
typedef float  f32x16 __attribute__((ext_vector_type(16)));
typedef unsigned short u16x8 __attribute__((ext_vector_type(8)));

#define M_ROWS 16384
#define K_IN   2048
#define N_OUT  8192
#define N_HARM 256

__device__ inline unsigned short f2bf(float f) {
    union { float f; uint32_t u; } c; c.f = f;
    uint32_t u = c.u;
    uint32_t r = (u + 0x7fffu + ((u >> 16) & 1u)) >> 16;  // RNE
    return (unsigned short)r;
}

__device__ inline bf16x8 cvt8(f32x4 a, f32x4 b) {
    bf16x8 r;
    r[0] = (__bf16)a[0]; r[1] = (__bf16)a[1]; r[2] = (__bf16)a[2]; r[3] = (__bf16)a[3];
    r[4] = (__bf16)b[0]; r[5] = (__bf16)b[1]; r[6] = (__bf16)b[2]; r[7] = (__bf16)b[3];
    return r;
}

#define GLDS(src, dst) \
    __builtin_amdgcn_global_load_lds((const __attribute__((address_space(1))) void*)(src), \
                                     (__attribute__((address_space(3))) void*)(dst), 16, 0, 0)

// ---- fp32 -> bf16 conversion (basis) ----
__global__ __launch_bounds__(256) void cvt_bf16(const float* __restrict__ in,
                                                unsigned short* __restrict__ out) {
    size_t i = ((size_t)blockIdx.x * 256 + threadIdx.x) * 8;
    f32x4 v0 = *(const f32x4*)(in + i);
    f32x4 v1 = *(const f32x4*)(in + i + 4);
    u16x8 o;
    o[0] = f2bf(v0[0]); o[1] = f2bf(v0[1]); o[2] = f2bf(v0[2]); o[3] = f2bf(v0[3]);
    o[4] = f2bf(v1[0]); o[5] = f2bf(v1[1]); o[6] = f2bf(v1[2]); o[7] = f2bf(v1[3]);
    *(u16x8*)(out + i) = o;
}

// ---- w_real = amp * cos(phase) -> bf16 (row-major [8192][256]) ----
__global__ __launch_bounds__(256) void wreal_bf16(const float* __restrict__ phase,
                                                  const float* __restrict__ amp,
                                                  unsigned short* __restrict__ out) {
    size_t i = ((size_t)blockIdx.x * 256 + threadIdx.x) * 8;
    f32x4 p0 = *(const f32x4*)(phase + i);
    f32x4 p1 = *(const f32x4*)(phase + i + 4);
    f32x4 a0 = *(const f32x4*)(amp + i);
    f32x4 a1 = *(const f32x4*)(amp + i + 4);
    u16x8 o;
    o[0] = f2bf(a0[0] * cosf(p0[0])); o[1] = f2bf(a0[1] * cosf(p0[1]));
    o[2] = f2bf(a0[2] * cosf(p0[2])); o[3] = f2bf(a0[3] * cosf(p0[3]));
    o[4] = f2bf(a1[0] * cosf(p1[0])); o[5] = f2bf(a1[1] * cosf(p1[1]));
    o[6] = f2bf(a1[2] * cosf(p1[2])); o[7] = f2bf(a1[3] * cosf(p1[3]));
    *(u16x8*)(out + i) = o;
}

// ---- gemm1: resonance[M,256] = x_f32[M,2048] @ basis_bf16[256,2048]^T ----
// (unchanged from round 3 — verified)
__global__ __launch_bounds__(256) void gemm1_fused(const float* __restrict__ A,
                                                   const unsigned short* __restrict__ B,
                                                   unsigned short* __restrict__ C) {
    __shared__ float          Asm[2][32 * 64];    // 16 KB
    __shared__ unsigned short Bsm[2][256 * 64];   // 64 KB

    const int tid  = threadIdx.x;
    const int lane = tid & 63;
    const int wv   = tid >> 6;
    const int bm0  = blockIdx.x * 32;

    const float* srcA[2];
#pragma unroll
    for (int q = 0; q < 2; ++q) {
        int L = q * 256 + tid;
        int r = L >> 4, p = L & 15;
        int c = p ^ (r & 15);
        srcA[q] = A + (size_t)(bm0 + r) * K_IN + c * 4;
    }
    const unsigned short* srcB[8];
#pragma unroll
    for (int q = 0; q < 8; ++q) {
        int L = q * 256 + tid;
        int r = L >> 3, p = L & 7;
        int c = p ^ (r & 7);
        srcB[q] = B + (size_t)r * K_IN + c * 8;
    }
    const int dA = wv * 256 + lane * 4;   // floats, + q*1024
    const int dB = wv * 512 + lane * 8;   // shorts, + q*2048

    f32x16 acc[2];
#pragma unroll
    for (int nf = 0; nf < 2; ++nf)
#pragma unroll
        for (int e = 0; e < 16; ++e) acc[nf][e] = 0.f;

    const int r   = lane & 31;
    const int g   = lane >> 5;
    const int r15 = r & 15;
    const int colb = wv * 64;

#pragma unroll
    for (int q = 0; q < 2; ++q) GLDS(srcA[q], &Asm[0][q * 1024 + dA]);
#pragma unroll
    for (int q = 0; q < 8; ++q) GLDS(srcB[q], &Bsm[0][q * 2048 + dB]);
    __syncthreads();

    for (int t = 0; t < 32; ++t) {
        const int buf = t & 1;
        if (t + 1 < 32) {
            const int k0 = (t + 1) * 64;
#pragma unroll
            for (int q = 0; q < 2; ++q) GLDS(srcA[q] + k0, &Asm[buf ^ 1][q * 1024 + dA]);
#pragma unroll
            for (int q = 0; q < 8; ++q) GLDS(srcB[q] + k0, &Bsm[buf ^ 1][q * 2048 + dB]);
        }

        bf16x8 af[4];
#pragma unroll
        for (int ks = 0; ks < 4; ++ks) {
            const int c0 = g * 2 + ks * 4;
            f32x4 lo = *(const f32x4*)&Asm[buf][r * 64 + ((c0)     ^ r15) * 4];
            f32x4 hi = *(const f32x4*)&Asm[buf][r * 64 + ((c0 + 1) ^ r15) * 4];
            af[ks] = cvt8(lo, hi);
        }
#pragma unroll
        for (int nf = 0; nf < 2; ++nf) {
            const int rB = colb + nf * 32 + r;
            const int r7 = rB & 7;
#pragma unroll
            for (int ks = 0; ks < 4; ++ks) {
                const int cB = g + ks * 2;
                bf16x8 bfrag = *(const bf16x8*)&Bsm[buf][rB * 64 + (cB ^ r7) * 8];
                acc[nf] = __builtin_amdgcn_mfma_f32_32x32x16_bf16(af[ks], bfrag, acc[nf], 0, 0, 0);
            }
        }
        __syncthreads();
    }

#pragma unroll
    for (int nf = 0; nf < 2; ++nf)
#pragma unroll
        for (int reg = 0; reg < 16; ++reg) {
            int row = bm0 + (reg & 3) + 8 * (reg >> 2) + 4 * g;
            int col = colb + nf * 32 + r;
            C[(size_t)row * N_HARM + col] = f2bf(acc[nf][reg]);
        }
}

// ---- gemm2_pipe: out[M][8192] = rb[M][256] @ wreal[8192][256]^T ----
// (unchanged from round 6)
__global__ __launch_bounds__(256) void gemm2_pipe(const unsigned short* __restrict__ A,
                                                  const unsigned short* __restrict__ B,
                                                  float* __restrict__ Cv) {
    __shared__ unsigned short As[3][4096];   // 8 KB x3
    __shared__ unsigned short Bs[3][4096];   // 8 KB x3

    const int tid  = threadIdx.x;
    const int lane = tid & 63;
    const int wv   = tid >> 6;
    const int wr   = wv >> 1;
    const int wc   = wv & 1;
    const int bm0  = blockIdx.y * 128;
    const int bn0  = blockIdx.x * 128;

    const unsigned short* srcA[2];
    const unsigned short* srcB[2];
#pragma unroll
    for (int q = 0; q < 2; ++q) {
        int L = q * 256 + tid;
        int lrow = L >> 3, chp = L & 7;
        int ch = chp ^ (lrow & 7);
        int m = (ch >> 2) * 64 + lrow;
        int k = (ch & 3) * 8;
        srcA[q] = A + (size_t)(bm0 + m) * N_HARM + k;
        srcB[q] = B + (size_t)(bn0 + m) * N_HARM + k;
    }
    const int dst = tid * 8;   // shorts; + q*2048

#define STAGE2(b, t) do { \
    GLDS(srcA[0] + (t) * 32, &As[b][dst]);        \
    GLDS(srcA[1] + (t) * 32, &As[b][2048 + dst]); \
    GLDS(srcB[0] + (t) * 32, &Bs[b][dst]);        \
    GLDS(srcB[1] + (t) * 32, &Bs[b][2048 + dst]); } while (0)

    f32x16 acc[2][2];
#pragma unroll
    for (int mi = 0; mi < 2; ++mi)
#pragma unroll
        for (int nj = 0; nj < 2; ++nj)
#pragma unroll
            for (int e = 0; e < 16; ++e) acc[mi][nj][e] = 0.f;

    const int r  = lane & 31;
    const int g  = lane >> 5;
    const int r7 = r & 7;

    STAGE2(0, 0);
    STAGE2(1, 1);

#pragma unroll
    for (int t = 0; t < 8; ++t) {
        if (t == 7) { asm volatile("s_waitcnt vmcnt(0)" ::: "memory"); }
        else        { asm volatile("s_waitcnt vmcnt(4)" ::: "memory"); }
        __builtin_amdgcn_s_barrier();
        if (t + 2 < 8) STAGE2((t + 2) % 3, t + 2);

        const int b = t % 3;
        bf16x8 af[2][2], bfx[2][2];
#pragma unroll
        for (int mi = 0; mi < 2; ++mi)
#pragma unroll
            for (int ks = 0; ks < 2; ++ks) {
                af[mi][ks]  = *(const bf16x8*)&As[b][(mi * 32 + r) * 64 + ((wr * 4 + ks * 2 + g) ^ r7) * 8];
                bfx[mi][ks] = *(const bf16x8*)&Bs[b][(mi * 32 + r) * 64 + ((wc * 4 + ks * 2 + g) ^ r7) * 8];
            }
#pragma unroll
        for (int ks = 0; ks < 2; ++ks)
#pragma unroll
            for (int mi = 0; mi < 2; ++mi)
#pragma unroll
                for (int nj = 0; nj < 2; ++nj)
                    acc[mi][nj] = __builtin_amdgcn_mfma_f32_32x32x16_bf16(af[mi][ks], bfx[nj][ks], acc[mi][nj], 0, 0, 0);
    }
#undef STAGE2

#pragma unroll
    for (int mi = 0; mi < 2; ++mi)
#pragma unroll
        for (int nj = 0; nj < 2; ++nj)
#pragma unroll
            for (int reg = 0; reg < 16; ++reg) {
                int row = bm0 + wr * 64 + mi * 32 + (reg & 3) + 8 * (reg >> 2) + 4 * g;
                int col = bn0 + wc * 64 + nj * 32 + r;
                Cv[(size_t)row * N_OUT + col] = acc[mi][nj][reg];
            }
}

extern "C" void kernel_launch(void* const* d_in, const int* in_sizes, int n_in,
                              void* d_out, int out_size, void* d_ws, size_t ws_size,
                              hipStream_t stream) {
    const float* x     = (const float*)d_in[0];   // [4,4096,2048]
    const float* basis = (const float*)d_in[1];   // [256,2048]
    const float* phase = (const float*)d_in[2];   // [8192,256]
    const float* amp   = (const float*)d_in[3];   // [8192,256]
    float* out = (float*)d_out;                   // [4,4096,8192] fp32

    char* ws = (char*)d_ws;
    unsigned short* bb  = (unsigned short*)(ws);             // basis bf16: 1 MB
    unsigned short* wrb = (unsigned short*)(ws + 1048576);   // wreal bf16: 4 MB
    unsigned short* rb  = (unsigned short*)(ws + 5242880);   // resonance:  8 MB

    cvt_bf16<<<dim3(256), dim3(256), 0, stream>>>(basis, bb);
    wreal_bf16<<<dim3(1024), dim3(256), 0, stream>>>(phase, amp, wrb);

    gemm1_fused<<<dim3(M_ROWS / 32), dim3(256), 0, stream>>>(x, bb, rb);

    // MEASUREMENT: gemm2 launched 3x (idempotent). g2 = (dur - 210us)/2.
    gemm2_pipe<<<dim3(N_OUT / 128, M_ROWS / 128), dim3(256), 0, stream>>>(rb, wrb, out);
    gemm2_pipe<<<dim3(N_OUT / 128, M_ROWS / 128), dim3(256), 0, stream>>>(rb, wrb, out);
    gemm2_pipe<<<dim3(N_OUT / 128, M_ROWS / 128), dim3(256), 0, stream>>>(rb, wrb, out);
}

// Round 9
// 188.535 us; speedup vs baseline: 2.7524x; 2.7524x over previous
//
#include <hip/hip_runtime.h>
#include <hip/hip_bf16.h>
#include <stdint.h>
#include <stddef.h>

// HoloLinear factored bf16 MFMA pipeline:
//   resonance[16384,256] = x_f32[16384,2048] @ basis_bf16[256,2048]^T
//   out[16384,8192]      = resonance_bf16 @ wreal_bf16[8192,256]^T
//
// gemm1: (verified r3) fused fp32->bf16, 32x256 tile, BK=64, 32x32x16 MFMA.
// gemm2: N-panel-stationary M-streaming, B-frags in registers (full K=256),
//        A 32-row tiles in TRIPLE-buffered LDS (race-proof: WAR distance =
//        2 barriers), r3-verified issue order (GLDS top, barrier bottom).

typedef __bf16 bf16x8 __attribute__((ext_vector_type(8)));
typedef float  f32x4  __attribute__((ext_vector_type(4)));
typedef float  f32x16 __attribute__((ext_vector_type(16)));
typedef unsigned short u16x8 __attribute__((ext_vector_type(8)));

#define M_ROWS 16384
#define K_IN   2048
#define N_OUT  8192
#define N_HARM 256

__device__ inline unsigned short f2bf(float f) {
    union { float f; uint32_t u; } c; c.f = f;
    uint32_t u = c.u;
    uint32_t r = (u + 0x7fffu + ((u >> 16) & 1u)) >> 16;  // RNE
    return (unsigned short)r;
}

__device__ inline bf16x8 cvt8(f32x4 a, f32x4 b) {
    bf16x8 r;
    r[0] = (__bf16)a[0]; r[1] = (__bf16)a[1]; r[2] = (__bf16)a[2]; r[3] = (__bf16)a[3];
    r[4] = (__bf16)b[0]; r[5] = (__bf16)b[1]; r[6] = (__bf16)b[2]; r[7] = (__bf16)b[3];
    return r;
}

#define GLDS(src, dst) \
    __builtin_amdgcn_global_load_lds((const __attribute__((address_space(1))) void*)(src), \
                                     (__attribute__((address_space(3))) void*)(dst), 16, 0, 0)

// ---- fp32 -> bf16 conversion (basis) ----
__global__ __launch_bounds__(256) void cvt_bf16(const float* __restrict__ in,
                                                unsigned short* __restrict__ out) {
    size_t i = ((size_t)blockIdx.x * 256 + threadIdx.x) * 8;
    f32x4 v0 = *(const f32x4*)(in + i);
    f32x4 v1 = *(const f32x4*)(in + i + 4);
    u16x8 o;
    o[0] = f2bf(v0[0]); o[1] = f2bf(v0[1]); o[2] = f2bf(v0[2]); o[3] = f2bf(v0[3]);
    o[4] = f2bf(v1[0]); o[5] = f2bf(v1[1]); o[6] = f2bf(v1[2]); o[7] = f2bf(v1[3]);
    *(u16x8*)(out + i) = o;
}

// ---- w_real = amp * cos(phase) -> bf16 (row-major [8192][256]) ----
__global__ __launch_bounds__(256) void wreal_bf16(const float* __restrict__ phase,
                                                  const float* __restrict__ amp,
                                                  unsigned short* __restrict__ out) {
    size_t i = ((size_t)blockIdx.x * 256 + threadIdx.x) * 8;
    f32x4 p0 = *(const f32x4*)(phase + i);
    f32x4 p1 = *(const f32x4*)(phase + i + 4);
    f32x4 a0 = *(const f32x4*)(amp + i);
    f32x4 a1 = *(const f32x4*)(amp + i + 4);
    u16x8 o;
    o[0] = f2bf(a0[0] * cosf(p0[0])); o[1] = f2bf(a0[1] * cosf(p0[1]));
    o[2] = f2bf(a0[2] * cosf(p0[2])); o[3] = f2bf(a0[3] * cosf(p0[3]));
    o[4] = f2bf(a1[0] * cosf(p1[0])); o[5] = f2bf(a1[1] * cosf(p1[1]));
    o[6] = f2bf(a1[2] * cosf(p1[2])); o[7] = f2bf(a1[3] * cosf(p1[3]));
    *(u16x8*)(out + i) = o;
}

// ---- gemm1: resonance[M,256] = x_f32[M,2048] @ basis_bf16[256,2048]^T ----
// (unchanged from round 3 — verified)
__global__ __launch_bounds__(256) void gemm1_fused(const float* __restrict__ A,
                                                   const unsigned short* __restrict__ B,
                                                   unsigned short* __restrict__ C) {
    __shared__ float          Asm[2][32 * 64];    // 16 KB
    __shared__ unsigned short Bsm[2][256 * 64];   // 64 KB

    const int tid  = threadIdx.x;
    const int lane = tid & 63;
    const int wv   = tid >> 6;
    const int bm0  = blockIdx.x * 32;

    const float* srcA[2];
#pragma unroll
    for (int q = 0; q < 2; ++q) {
        int L = q * 256 + tid;
        int r = L >> 4, p = L & 15;
        int c = p ^ (r & 15);
        srcA[q] = A + (size_t)(bm0 + r) * K_IN + c * 4;
    }
    const unsigned short* srcB[8];
#pragma unroll
    for (int q = 0; q < 8; ++q) {
        int L = q * 256 + tid;
        int r = L >> 3, p = L & 7;
        int c = p ^ (r & 7);
        srcB[q] = B + (size_t)r * K_IN + c * 8;
    }
    const int dA = wv * 256 + lane * 4;   // floats, + q*1024
    const int dB = wv * 512 + lane * 8;   // shorts, + q*2048

    f32x16 acc[2];
#pragma unroll
    for (int nf = 0; nf < 2; ++nf)
#pragma unroll
        for (int e = 0; e < 16; ++e) acc[nf][e] = 0.f;

    const int r   = lane & 31;
    const int g   = lane >> 5;
    const int r15 = r & 15;
    const int colb = wv * 64;

#pragma unroll
    for (int q = 0; q < 2; ++q) GLDS(srcA[q], &Asm[0][q * 1024 + dA]);
#pragma unroll
    for (int q = 0; q < 8; ++q) GLDS(srcB[q], &Bsm[0][q * 2048 + dB]);
    __syncthreads();

    for (int t = 0; t < 32; ++t) {
        const int buf = t & 1;
        if (t + 1 < 32) {
            const int k0 = (t + 1) * 64;
#pragma unroll
            for (int q = 0; q < 2; ++q) GLDS(srcA[q] + k0, &Asm[buf ^ 1][q * 1024 + dA]);
#pragma unroll
            for (int q = 0; q < 8; ++q) GLDS(srcB[q] + k0, &Bsm[buf ^ 1][q * 2048 + dB]);
        }

        bf16x8 af[4];
#pragma unroll
        for (int ks = 0; ks < 4; ++ks) {
            const int c0 = g * 2 + ks * 4;
            f32x4 lo = *(const f32x4*)&Asm[buf][r * 64 + ((c0)     ^ r15) * 4];
            f32x4 hi = *(const f32x4*)&Asm[buf][r * 64 + ((c0 + 1) ^ r15) * 4];
            af[ks] = cvt8(lo, hi);
        }
#pragma unroll
        for (int nf = 0; nf < 2; ++nf) {
            const int rB = colb + nf * 32 + r;
            const int r7 = rB & 7;
#pragma unroll
            for (int ks = 0; ks < 4; ++ks) {
                const int cB = g + ks * 2;
                bf16x8 bfrag = *(const bf16x8*)&Bsm[buf][rB * 64 + (cB ^ r7) * 8];
                acc[nf] = __builtin_amdgcn_mfma_f32_32x32x16_bf16(af[ks], bfrag, acc[nf], 0, 0, 0);
            }
        }
        __syncthreads();
    }

#pragma unroll
    for (int nf = 0; nf < 2; ++nf)
#pragma unroll
        for (int reg = 0; reg < 16; ++reg) {
            int row = bm0 + (reg & 3) + 8 * (reg >> 2) + 4 * g;
            int col = colb + nf * 32 + r;
            C[(size_t)row * N_HARM + col] = f2bf(acc[nf][reg]);
        }
}

// ---- gemm2_nstream: out[M][8192] = rb[M][256] @ wreal[8192][256]^T ----
// Grid (32 panels, 16 row-groups), 512 thr = 8 waves. Wave wv owns cols
// panel*256 + wv*32, full K=256 of B in registers (16 bf16x8). Block streams
// 32 M-steps of 32 rows. A staged to TRIPLE-buffered swizzled LDS (48 KB):
// GLDS(t+1) writes As[(t+1)%3], last read at t-2 -> WAR distance 2 barriers.
// Issue order = r3-verified skeleton: GLDS top, __syncthreads bottom.
__global__ __launch_bounds__(512) void gemm2_nstream(const unsigned short* __restrict__ A,
                                                     const unsigned short* __restrict__ B,
                                                     float* __restrict__ Cv) {
    __shared__ unsigned short As[3][32 * 256];   // 16 KB x3

    const int tid  = threadIdx.x;
    const int lane = tid & 63;
    const int wv   = tid >> 6;     // 0..7 = col slot
    const int r    = lane & 31;
    const int g    = lane >> 5;
    const int r7   = r & 7;

    const int col0  = blockIdx.x * 256 + wv * 32;   // wave's 32 cols
    const int mbase = blockIdx.y * 1024;

    // B fragments in registers: full K (16 k-steps), chunk c = ks*2+g, k = c*8
    bf16x8 bf[16];
#pragma unroll
    for (int ks = 0; ks < 16; ++ks)
        bf[ks] = *(const bf16x8*)(B + (size_t)(col0 + r) * N_HARM + ks * 16 + g * 8);

    // A staging sources (inverse-swizzled): LDS slot L -> row=L>>5, slot=L&31,
    // logical chunk c = slot ^ (row&7)
    const unsigned short* srcA[2];
#pragma unroll
    for (int q = 0; q < 2; ++q) {
        int L = q * 512 + tid;
        int row = L >> 5, slot = L & 31;
        int c = slot ^ (row & 7);
        srcA[q] = A + (size_t)(mbase + row) * N_HARM + c * 8;
    }
    const int dstA = tid * 8;   // shorts; +q*4096

    // prologue: stage step 0 into As[0]
    GLDS(srcA[0], &As[0][dstA]);
    GLDS(srcA[1], &As[0][4096 + dstA]);
    __syncthreads();

    for (int t = 0; t < 32; ++t) {
        const int cur = t % 3;
        if (t + 1 < 32) {
            const int nxt = (t + 1) % 3;
            __builtin_amdgcn_sched_barrier(0);
            GLDS(srcA[0] + (t + 1) * 32 * N_HARM, &As[nxt][dstA]);
            GLDS(srcA[1] + (t + 1) * 32 * N_HARM, &As[nxt][4096 + dstA]);
            __builtin_amdgcn_sched_barrier(0);
        }

        f32x16 acc;
#pragma unroll
        for (int e = 0; e < 16; ++e) acc[e] = 0.f;

#pragma unroll
        for (int ks = 0; ks < 16; ++ks) {
            const int c = ks * 2 + g;
            bf16x8 af = *(const bf16x8*)&As[cur][r * 256 + (c ^ r7) * 8];
            acc = __builtin_amdgcn_mfma_f32_32x32x16_bf16(af, bf[ks], acc, 0, 0, 0);
        }

        // C/D: col = lane&31, row = (reg&3) + 8*(reg>>2) + 4*g
        const int m0 = mbase + t * 32;
#pragma unroll
        for (int reg = 0; reg < 16; ++reg) {
            int row = m0 + (reg & 3) + 8 * (reg >> 2) + 4 * g;
            Cv[(size_t)row * N_OUT + col0 + r] = acc[reg];
        }

        __syncthreads();   // drains GLDS(t+1) + all waves' reads of As[cur]
    }
}

extern "C" void kernel_launch(void* const* d_in, const int* in_sizes, int n_in,
                              void* d_out, int out_size, void* d_ws, size_t ws_size,
                              hipStream_t stream) {
    const float* x     = (const float*)d_in[0];   // [4,4096,2048]
    const float* basis = (const float*)d_in[1];   // [256,2048]
    const float* phase = (const float*)d_in[2];   // [8192,256]
    const float* amp   = (const float*)d_in[3];   // [8192,256]
    float* out = (float*)d_out;                   // [4,4096,8192] fp32

    char* ws = (char*)d_ws;
    unsigned short* bb  = (unsigned short*)(ws);             // basis bf16: 1 MB
    unsigned short* wrb = (unsigned short*)(ws + 1048576);   // wreal bf16: 4 MB
    unsigned short* rb  = (unsigned short*)(ws + 5242880);   // resonance:  8 MB

    cvt_bf16<<<dim3(256), dim3(256), 0, stream>>>(basis, bb);
    wreal_bf16<<<dim3(1024), dim3(256), 0, stream>>>(phase, amp, wrb);

    // resonance[16384,256] = x @ bb^T  (fp32 A staged to LDS, fused cvt)
    gemm1_fused<<<dim3(M_ROWS / 32), dim3(256), 0, stream>>>(x, bb, rb);
    // out[16384,8192] = rb @ wrb^T  (N-panel-stationary, B in registers)
    gemm2_nstream<<<dim3(32, 16), dim3(512), 0, stream>>>(rb, wrb, out);
}